// Round 1
// baseline (200.889 us; speedup 1.0000x reference)
//
#include <hip/hip_runtime.h>

typedef __attribute__((ext_vector_type(8))) short bf16x8;
typedef __attribute__((ext_vector_type(4))) float f32x4;

#define N 4096

__device__ __forceinline__ unsigned short f2bf_rne(float f) {
  unsigned int u = __float_as_uint(f);
  u += 0x7fffu + ((u >> 16) & 1u);   // round-to-nearest-even
  return (unsigned short)(u >> 16);
}

// One block per row (8192 rows total: Z then Y). Computes fp32 row norm and
// bf16 copy of the row.
__global__ __launch_bounds__(256) void prep_kernel(
    const float* __restrict__ Z, const float* __restrict__ Y,
    unsigned short* __restrict__ Zb, unsigned short* __restrict__ Yb,
    float* __restrict__ norms) {
  const int r = blockIdx.x;            // 0..8191
  const bool isZ = (r < N);
  const int rr = isZ ? r : r - N;
  const float* __restrict__ src = (isZ ? Z : Y) + (size_t)rr * N;
  unsigned short* __restrict__ dst = (isZ ? Zb : Yb) + (size_t)rr * N;
  const int t = threadIdx.x;           // 0..255

  float s = 0.f;
#pragma unroll
  for (int j = 0; j < 4; ++j) {
    const float4 v = ((const float4*)src)[j * 256 + t];
    s += v.x * v.x + v.y * v.y + v.z * v.z + v.w * v.w;
    short4 o;
    o.x = (short)f2bf_rne(v.x);
    o.y = (short)f2bf_rne(v.y);
    o.z = (short)f2bf_rne(v.z);
    o.w = (short)f2bf_rne(v.w);
    ((short4*)dst)[j * 256 + t] = o;
  }
  // 64-wide wave reduce, then cross-wave via LDS
#pragma unroll
  for (int off = 32; off > 0; off >>= 1) s += __shfl_down(s, off, 64);
  __shared__ float red[4];
  const int lane = t & 63, w = t >> 6;
  if (lane == 0) red[w] = s;
  __syncthreads();
  if (t == 0) norms[r] = sqrtf(red[0] + red[1] + red[2] + red[3]);
}

// m97-structure GEMM: C = A * B^T (both row-major bf16), fused cosine epilogue.
// 128x128 tile, BK=32, 4 waves each computing a 64x64 sub-tile as 4x4
// mfma_f32_16x16x32_bf16 fragments. global_load_lds width-16 staging.
__global__ __launch_bounds__(256) void gemm_kernel(
    const unsigned short* __restrict__ A,   // Zb [N][N]
    const unsigned short* __restrict__ B,   // Yb [N][N]
    const float* __restrict__ norms,        // [2N]: nx then ny
    float* __restrict__ out) {
  __shared__ __align__(16) unsigned short Asm[128 * 32];
  __shared__ __align__(16) unsigned short Bsm[128 * 32];

  // XCD-aware mapping: 1024 blocks, 8 XCDs -> XCD x owns tile rows 4x..4x+3,
  // iterates col-major within its band (B-panel reuse in its private L2).
  const int bid = blockIdx.x;
  const int xcd = bid & 7;
  const int c = bid >> 3;                  // 0..127
  const int tile_col = c >> 2;             // 0..31
  const int tile_row = (xcd << 2) + (c & 3);

  const int tid = threadIdx.x;
  const int l = tid & 63;
  const int w = tid >> 6;
  const int wr = w >> 1, wc = w & 1;

  // staging: thread tid loads 16B = 8 bf16; row = q*64 + tid/4, kcol = (tid&3)*8
  const int srow = tid >> 2;
  const int scol = (tid & 3) * 8;
  const size_t ga0 = (size_t)(tile_row * 128 + srow) * N + scol;
  const size_t gb0 = (size_t)(tile_col * 128 + srow) * N + scol;
  // LDS dest: wave-uniform base + lane*16 (hardware rule); layout is linear
  // row-major [128][32] so base = w*1024 + q*4096 bytes.
  char* lA = (char*)Asm + w * 1024;
  char* lB = (char*)Bsm + w * 1024;

  // fragment read offsets (elements): lane l reads row (l&15), k = (l>>4)*8
  int aoff[4], boff[4];
#pragma unroll
  for (int i = 0; i < 4; ++i) {
    aoff[i] = (wr * 64 + i * 16 + (l & 15)) * 32 + (l >> 4) * 8;
    boff[i] = (wc * 64 + i * 16 + (l & 15)) * 32 + (l >> 4) * 8;
  }

  f32x4 acc[4][4];
#pragma unroll
  for (int i = 0; i < 4; ++i)
#pragma unroll
    for (int j = 0; j < 4; ++j)
      acc[i][j] = (f32x4){0.f, 0.f, 0.f, 0.f};

  for (int kt = 0; kt < N; kt += 32) {
    __syncthreads();  // previous tile's compute done before overwrite
    __builtin_amdgcn_global_load_lds(
        (__attribute__((address_space(1))) void*)(A + ga0 + kt),
        (__attribute__((address_space(3))) void*)lA, 16, 0, 0);
    __builtin_amdgcn_global_load_lds(
        (__attribute__((address_space(1))) void*)(A + ga0 + (size_t)64 * N + kt),
        (__attribute__((address_space(3))) void*)(lA + 4096), 16, 0, 0);
    __builtin_amdgcn_global_load_lds(
        (__attribute__((address_space(1))) void*)(B + gb0 + kt),
        (__attribute__((address_space(3))) void*)lB, 16, 0, 0);
    __builtin_amdgcn_global_load_lds(
        (__attribute__((address_space(1))) void*)(B + gb0 + (size_t)64 * N + kt),
        (__attribute__((address_space(3))) void*)(lB + 4096), 16, 0, 0);
    __syncthreads();  // compiler drains vmcnt before s_barrier -> tiles visible

    bf16x8 av[4], bv[4];
#pragma unroll
    for (int i = 0; i < 4; ++i) av[i] = *(const bf16x8*)(Asm + aoff[i]);
#pragma unroll
    for (int i = 0; i < 4; ++i) bv[i] = *(const bf16x8*)(Bsm + boff[i]);
#pragma unroll
    for (int i = 0; i < 4; ++i)
#pragma unroll
      for (int j = 0; j < 4; ++j)
        acc[i][j] = __builtin_amdgcn_mfma_f32_16x16x32_bf16(av[i], bv[j],
                                                            acc[i][j], 0, 0, 0);
  }

  // epilogue: C/D layout row=(l>>4)*4+r, col=l&15 (HW-verified m89/m91)
  const float* nx = norms;
  const float* ny = norms + N;
  const int row0 = tile_row * 128 + wr * 64 + ((l >> 4) * 4);
  const int col0 = tile_col * 128 + wc * 64 + (l & 15);
#pragma unroll
  for (int i = 0; i < 4; ++i) {
#pragma unroll
    for (int r = 0; r < 4; ++r) {
      const int row = row0 + i * 16 + r;
      const float nxr = nx[row];
#pragma unroll
      for (int j = 0; j < 4; ++j) {
        const int col = col0 + j * 16;
        const float denom = fmaxf(nxr * ny[col], 1e-8f);
        out[(size_t)row * N + col] = acc[i][j][r] / denom;
      }
    }
  }
}

extern "C" void kernel_launch(void* const* d_in, const int* in_sizes, int n_in,
                              void* d_out, int out_size, void* d_ws, size_t ws_size,
                              hipStream_t stream) {
  const float* Z = (const float*)d_in[0];
  const float* Y = (const float*)d_in[1];
  float* out = (float*)d_out;

  // workspace: Zb (32MB) | Yb (32MB) | norms (32KB)
  unsigned short* Zb = (unsigned short*)d_ws;
  unsigned short* Yb = Zb + (size_t)N * N;
  float* norms = (float*)(Yb + (size_t)N * N);

  prep_kernel<<<2 * N, 256, 0, stream>>>(Z, Y, Zb, Yb, norms);
  gemm_kernel<<<(N / 128) * (N / 128), 256, 0, stream>>>(Zb, Yb, norms, out);
}

// Round 2
// 149.165 us; speedup vs baseline: 1.3468x; 1.3468x over previous
//
#include <hip/hip_runtime.h>

typedef __attribute__((ext_vector_type(8))) short bf16x8;
typedef __attribute__((ext_vector_type(4))) float f32x4;
typedef unsigned short ushort_t;

#define N 4096
#define NT 128   // K-tiles of BK=32

__device__ __forceinline__ unsigned short f2bf_rne(float f) {
  unsigned int u = __float_as_uint(f);
  u += 0x7fffu + ((u >> 16) & 1u);   // round-to-nearest-even
  return (unsigned short)(u >> 16);
}

// One block per row (8192 rows: Z then Y). fp32 row norm + bf16 copy.
__global__ __launch_bounds__(256) void prep_kernel(
    const float* __restrict__ Z, const float* __restrict__ Y,
    ushort_t* __restrict__ Zb, ushort_t* __restrict__ Yb,
    float* __restrict__ norms) {
  const int r = blockIdx.x;
  const bool isZ = (r < N);
  const int rr = isZ ? r : r - N;
  const float* __restrict__ src = (isZ ? Z : Y) + (size_t)rr * N;
  ushort_t* __restrict__ dst = (isZ ? Zb : Yb) + (size_t)rr * N;
  const int t = threadIdx.x;

  float s = 0.f;
#pragma unroll
  for (int j = 0; j < 4; ++j) {
    const float4 v = ((const float4*)src)[j * 256 + t];
    s += v.x * v.x + v.y * v.y + v.z * v.z + v.w * v.w;
    short4 o;
    o.x = (short)f2bf_rne(v.x);
    o.y = (short)f2bf_rne(v.y);
    o.z = (short)f2bf_rne(v.z);
    o.w = (short)f2bf_rne(v.w);
    ((short4*)dst)[j * 256 + t] = o;
  }
#pragma unroll
  for (int off = 32; off > 0; off >>= 1) s += __shfl_down(s, off, 64);
  __shared__ float red[4];
  const int lane = t & 63, w = t >> 6;
  if (lane == 0) red[w] = s;
  __syncthreads();
  if (t == 0) norms[r] = sqrtf(red[0] + red[1] + red[2] + red[3]);
}

template <int VM>
__device__ __forceinline__ void vm_wait() {
  if constexpr (VM == 8) asm volatile("s_waitcnt vmcnt(8)" ::: "memory");
  else if constexpr (VM == 4) asm volatile("s_waitcnt vmcnt(4)" ::: "memory");
  else if constexpr (VM == 0) asm volatile("s_waitcnt vmcnt(0)" ::: "memory");
}

// 256x256 tile, BK=32, 8 waves (2M x 4N), 4-deep LDS ring, counted vmcnt.
__global__ __launch_bounds__(512, 2) void gemm_kernel(
    const ushort_t* __restrict__ A,   // Zb [N][N]
    const ushort_t* __restrict__ B,   // Yb [N][N]
    const float* __restrict__ norms,  // [2N]: nx then ny
    float* __restrict__ out) {
  // ring: buf*32768 bytes; within buf: A at +0, B at +16384 (each 256x32 bf16)
  __shared__ __align__(16) char smem[131072];

  const int bid = blockIdx.x;                 // 256 blocks, 256%8==0: bijective
  const int swz = (bid & 7) * 32 + (bid >> 3);
  const int tile_row = swz >> 4;              // 0..15
  const int tile_col = swz & 15;              // 0..15

  const int tid = threadIdx.x;
  const int l = tid & 63;
  const int w = tid >> 6;     // 0..7
  const int wr = w >> 2;      // 0..1  (M half)
  const int wc = w & 3;       // 0..3  (N quarter)
  const int li = l & 15;
  const int sl = l >> 4;

  // ---- staging: per-thread pre-swizzled global pointers -----------------
  // chunk = q*512 + tid writes LDS bytes [chunk*16, +16) (linear, HW rule).
  // LDS(row,slot) must hold global (row, slot ^ ((row>>1)&3))  [involution]
  const ushort_t* pgA[2];
  const ushort_t* pgB[2];
#pragma unroll
  for (int q = 0; q < 2; ++q) {
    const int ch = q * 512 + tid;
    const int row = ch >> 2, slot = ch & 3;
    const int ss = slot ^ ((row >> 1) & 3);
    pgA[q] = A + (size_t)(tile_row * 256 + row) * N + ss * 8;
    pgB[q] = B + (size_t)(tile_col * 256 + row) * N + ss * 8;
  }

  auto stageA = [&](int t, int buf) {
#pragma unroll
    for (int q = 0; q < 2; ++q)
      __builtin_amdgcn_global_load_lds(
          (__attribute__((address_space(1))) void*)(pgA[q] + t * 32),
          (__attribute__((address_space(3))) void*)(smem + buf * 32768 +
                                                    q * 8192 + w * 1024),
          16, 0, 0);
  };
  auto stageB = [&](int t, int buf) {
#pragma unroll
    for (int q = 0; q < 2; ++q)
      __builtin_amdgcn_global_load_lds(
          (__attribute__((address_space(1))) void*)(pgB[q] + t * 32),
          (__attribute__((address_space(3))) void*)(smem + buf * 32768 + 16384 +
                                                    q * 8192 + w * 1024),
          16, 0, 0);
  };

  // ---- fragment LDS byte offsets (within one matrix buffer) -------------
  // lane reads row base+li, 16B slot sl, swizzled: sl ^ ((li>>1)&3)
  const int ssl = sl ^ ((li >> 1) & 3);
  int offA[8], offB[4];
#pragma unroll
  for (int m = 0; m < 8; ++m)
    offA[m] = ((wr * 128 + m * 16 + li) * 32 + ssl * 8) * 2;
#pragma unroll
  for (int n = 0; n < 4; ++n)
    offB[n] = ((wc * 64 + n * 16 + li) * 32 + ssl * 8) * 2;

  f32x4 acc[8][4];
#pragma unroll
  for (int m = 0; m < 8; ++m)
#pragma unroll
    for (int n = 0; n < 4; ++n) acc[m][n] = (f32x4){0.f, 0.f, 0.f, 0.f};

  // ---- prologue: stage tiles 0,1,2; tile 0 guaranteed by vmcnt(8) -------
  stageA(0, 0); stageB(0, 0);
  stageA(1, 1); stageB(1, 1);
  stageA(2, 2); stageB(2, 2);
  vm_wait<8>();
  __builtin_amdgcn_s_barrier();

  // ---- per-tile body: 2 phases, stage t+3 into buf (t-1)&3 --------------
  // safety: buf (t+3)&3's old reads (tile t-1) all completed before the
  // barrier ending tile t-1 (lgkmcnt drained before its MFMAs); stage
  // issues are program-order after that barrier.
#define TILE_BODY(T, VMN, DOSTAGE)                                            \
  {                                                                           \
    const int buf_ = (T) & 3;                                                 \
    const char* pA_ = smem + buf_ * 32768;                                    \
    const char* pB_ = pA_ + 16384;                                            \
    bf16x8 av[4], aw[4], bv[4];                                               \
    _Pragma("unroll")                                                         \
    for (int m = 0; m < 4; ++m) av[m] = *(const bf16x8*)(pA_ + offA[m]);      \
    _Pragma("unroll")                                                         \
    for (int n = 0; n < 4; ++n) bv[n] = *(const bf16x8*)(pB_ + offB[n]);      \
    if (DOSTAGE) stageA((T) + 3, ((T) + 3) & 3);                              \
    __builtin_amdgcn_s_barrier();                                             \
    __builtin_amdgcn_s_setprio(1);                                            \
    _Pragma("unroll")                                                         \
    for (int m = 0; m < 4; ++m)                                               \
      _Pragma("unroll")                                                       \
      for (int n = 0; n < 4; ++n)                                             \
        acc[m][n] = __builtin_amdgcn_mfma_f32_16x16x32_bf16(av[m], bv[n],     \
                                                            acc[m][n], 0, 0, 0); \
    __builtin_amdgcn_s_setprio(0);                                            \
    __builtin_amdgcn_s_barrier();                                             \
    _Pragma("unroll")                                                         \
    for (int m = 0; m < 4; ++m) aw[m] = *(const bf16x8*)(pA_ + offA[m + 4]);  \
    if (DOSTAGE) stageB((T) + 3, ((T) + 3) & 3);                              \
    __builtin_amdgcn_s_barrier();                                             \
    __builtin_amdgcn_s_setprio(1);                                            \
    _Pragma("unroll")                                                         \
    for (int m = 0; m < 4; ++m)                                               \
      _Pragma("unroll")                                                       \
      for (int n = 0; n < 4; ++n)                                             \
        acc[m + 4][n] = __builtin_amdgcn_mfma_f32_16x16x32_bf16(              \
            aw[m], bv[n], acc[m + 4][n], 0, 0, 0);                            \
    __builtin_amdgcn_s_setprio(0);                                            \
    vm_wait<VMN>();                                                           \
    if ((VMN) >= 0) __builtin_amdgcn_s_barrier();                             \
  }

#pragma unroll 4
  for (int t = 0; t < 124; ++t) {   // 124 = 4*31: buf_ folds to constant
    TILE_BODY(t, 8, true);
  }
  TILE_BODY(124, 8, true);          // stages tile 127 (last)
  TILE_BODY(125, 4, false);         // tile 126 guaranteed
  TILE_BODY(126, 0, false);         // tile 127 guaranteed
  TILE_BODY(127, -1, false);        // final, no wait/barrier needed
#undef TILE_BODY

  // ---- epilogue: cosine normalize, C/D layout row=(l>>4)*4+r, col=l&15 --
  const float* nx = norms;
  const float* ny = norms + N;
  const int row0 = tile_row * 256 + wr * 128 + sl * 4;
  const int col0 = tile_col * 256 + wc * 64 + li;
#pragma unroll
  for (int m = 0; m < 8; ++m) {
#pragma unroll
    for (int r = 0; r < 4; ++r) {
      const int row = row0 + m * 16 + r;
      const float nxr = nx[row];
#pragma unroll
      for (int n = 0; n < 4; ++n) {
        const int col = col0 + n * 16;
        const float denom = fmaxf(nxr * ny[col], 1e-8f);
        out[(size_t)row * N + col] = acc[m][n][r] / denom;
      }
    }
  }
}

extern "C" void kernel_launch(void* const* d_in, const int* in_sizes, int n_in,
                              void* d_out, int out_size, void* d_ws, size_t ws_size,
                              hipStream_t stream) {
  const float* Z = (const float*)d_in[0];
  const float* Y = (const float*)d_in[1];
  float* out = (float*)d_out;

  ushort_t* Zb = (ushort_t*)d_ws;
  ushort_t* Yb = Zb + (size_t)N * N;
  float* norms = (float*)(Yb + (size_t)N * N);

  prep_kernel<<<2 * N, 256, 0, stream>>>(Z, Y, Zb, Yb, norms);
  gemm_kernel<<<(N / 256) * (N / 256), 512, 0, stream>>>(Zb, Yb, norms, out);
}